// Round 14
// baseline (109.377 us; speedup 1.0000x reference)
//
#include <hip/hip_runtime.h>

typedef __attribute__((ext_vector_type(8))) _Float16 half8;
typedef __attribute__((ext_vector_type(4))) _Float16 half4;
typedef __attribute__((ext_vector_type(2))) __fp16 fp16x2;
typedef __attribute__((ext_vector_type(4))) float f32x4;
typedef __attribute__((ext_vector_type(4))) unsigned int u32x4;
typedef __attribute__((ext_vector_type(2))) unsigned int u32x2;

#define NSEQ 2048
#define DIMM 1024
#define NH   16
#define HD   64

typedef const void __attribute__((address_space(1))) gvoid_t;
typedef void __attribute__((address_space(3))) svoid_t;

__device__ __forceinline__ void gload_lds16(const void* g, void* l) {
  __builtin_amdgcn_global_load_lds((gvoid_t*)g, (svoid_t*)l, 16, 0, 0);
}

union H2U { fp16x2 h; unsigned int u; };

// ---------------- fused fp32 -> fp16 convert (x, w_qkv, w_out in one launch) ----
__global__ __launch_bounds__(256) void cvt_all(const float* __restrict__ x,
                                               const float* __restrict__ wqkv,
                                               const float* __restrict__ wout,
                                               _Float16* __restrict__ xh,
                                               _Float16* __restrict__ wqkvh,
                                               _Float16* __restrict__ wouth) {
  int i = blockIdx.x * 256 + threadIdx.x;
  const float* src;
  _Float16* dst;
  int off;
  if (i < 524288) { src = x; dst = xh; off = i; }
  else if (i < 917504) { src = wqkv; dst = wqkvh; off = i - 524288; }
  else { src = wout; dst = wouth; off = i - 917504; }
  const float4* p = (const float4*)src + (size_t)off * 2;
  float4 v0 = p[0], v1 = p[1];
  half8 h;
  h[0] = (_Float16)v0.x; h[1] = (_Float16)v0.y; h[2] = (_Float16)v0.z; h[3] = (_Float16)v0.w;
  h[4] = (_Float16)v1.x; h[5] = (_Float16)v1.y; h[6] = (_Float16)v1.z; h[7] = (_Float16)v1.w;
  *((half8*)dst + off) = h;
}

// ---- NT GEMM mainloop (qkv): 128x128 tile, BK=32, 3-buf counted-vmcnt, 1 barrier/step.
__device__ __forceinline__ void gemm_mainloop_q(const _Float16* __restrict__ A,
                                                const _Float16* __restrict__ B,
                                                int am0, int bn0,
                                                _Float16* As, _Float16* Bs,   // [3][4096] each
                                                f32x4 acc[4][4]) {
  const int tid = threadIdx.x;
  const int w = tid >> 6, lane = tid & 63;
  const int lr = lane >> 2;
  const int lc = (lane & 3) * 8;
  const int wm = (w >> 1) * 64, wn = (w & 1) * 64;
  const int g = lane >> 4, ln = lane & 15;

#define GSTAGE_Q(buf, kk)                                                           \
  {                                                                                 \
    _Pragma("unroll")                                                               \
    for (int i = 0; i < 4; ++i) {                                                   \
      int c = w * 4 + i;                                                            \
      if (c < 8) {                                                                  \
        gload_lds16(A + (size_t)(am0 + c * 16 + lr) * 1024 + (kk) + lc,             \
                    As + (buf) * 4096 + c * 512);                                   \
      } else {                                                                      \
        int cb = c - 8;                                                             \
        gload_lds16(B + (size_t)(bn0 + cb * 16 + lr) * 1024 + (kk) + lc,            \
                    Bs + (buf) * 4096 + cb * 512);                                  \
      }                                                                             \
    }                                                                               \
  }

  GSTAGE_Q(0, 0)
  GSTAGE_Q(1, 32)
  for (int t = 0; t < 32; ++t) {
    if (t < 31) {
      asm volatile("s_waitcnt vmcnt(4)" ::: "memory");
    } else {
      asm volatile("s_waitcnt vmcnt(0)" ::: "memory");
    }
    __builtin_amdgcn_s_barrier();
    if (t < 30) GSTAGE_Q((t + 2) % 3, (t + 2) * 32);
    const _Float16* as_ = As + (t % 3) * 4096;
    const _Float16* bs_ = Bs + (t % 3) * 4096;
    half8 af[4], bf[4];
#pragma unroll
    for (int mi = 0; mi < 4; ++mi)
      af[mi] = *(const half8*)(as_ + (wm + mi * 16 + ln) * 32 + g * 8);
#pragma unroll
    for (int ni = 0; ni < 4; ++ni)
      bf[ni] = *(const half8*)(bs_ + (wn + ni * 16 + ln) * 32 + g * 8);
#pragma unroll
    for (int mi = 0; mi < 4; ++mi)
#pragma unroll
      for (int ni = 0; ni < 4; ++ni)
        acc[mi][ni] = __builtin_amdgcn_mfma_f32_16x16x32_f16(af[mi], bf[ni], acc[mi][ni], 0, 0, 0);
  }
}

// ---------------- kernel 1: qkv = x @ w_qkv^T, scatter epilogue ----------------
union SmemQKV {
  struct { _Float16 a[3 * 128 * 32]; _Float16 b[3 * 128 * 32]; } ab;  // 48 KB
  _Float16 t[128 * 136];                                             // 34 KB
};

// Q pre-scaled by SCALE * log2(e) so attention works in exp2 domain.
#define QSCALE 0.0450843450f

__global__ __launch_bounds__(256) void gemm_qkv(const _Float16* __restrict__ x,
                                                const _Float16* __restrict__ wqkv,
                                                _Float16* __restrict__ qh,
                                                _Float16* __restrict__ kh,
                                                _Float16* __restrict__ vt) {
  __shared__ SmemQKV sh;
  f32x4 acc[4][4];
#pragma unroll
  for (int i = 0; i < 4; ++i)
#pragma unroll
    for (int j = 0; j < 4; ++j) acc[i][j] = (f32x4){0.f, 0.f, 0.f, 0.f};
  const int bm = blockIdx.x, bn = blockIdx.y;
  gemm_mainloop_q(x, wqkv, bm * 128, bn * 128, sh.ab.a, sh.ab.b, acc);

  const int tid = threadIdx.x;
  const int w = tid >> 6, lane = tid & 63;
  const int g = lane >> 4, ln = lane & 15;
  const int wm = (w >> 1) * 64, wn = (w & 1) * 64;
  const int sec = bn >> 3;
  const int cbase = (bn & 7) * 128;

  if (sec < 2) {
    _Float16* dst = (sec == 0) ? qh : kh;
    const float scale = (sec == 0) ? QSCALE : 1.0f;
#pragma unroll
    for (int mi = 0; mi < 4; ++mi) {
      int row = bm * 128 + wm + mi * 16 + g * 4;
      int bidx = row >> 11, nidx = row & 2047;
#pragma unroll
      for (int ni = 0; ni < 4; ++ni) {
        int col = cbase + wn + ni * 16 + ln;
        int h = col >> 6, d = col & 63;
        _Float16* p = dst + ((size_t)(bidx * NH + h) * NSEQ + nidx) * HD + d;
#pragma unroll
        for (int r = 0; r < 4; ++r) p[r * HD] = (_Float16)(acc[mi][ni][r] * scale);
      }
    }
  } else {
    __syncthreads();
#pragma unroll
    for (int mi = 0; mi < 4; ++mi)
#pragma unroll
      for (int ni = 0; ni < 4; ++ni)
#pragma unroll
        for (int r = 0; r < 4; ++r)
          sh.t[(wn + ni * 16 + ln) * 136 + wm + mi * 16 + g * 4 + r] = (_Float16)acc[mi][ni][r];
    __syncthreads();
    const int row0 = bm * 128;
    const int bidx = row0 >> 11, n0 = row0 & 2047;
#pragma unroll
    for (int i = 0; i < 8; ++i) {
      int ci = i * 256 + tid;
      int drow = ci >> 4, nofs = (ci & 15) * 8;
      int col = cbase + drow;
      int h = col >> 6, d = col & 63;
      u32x4 val = *(const u32x4*)(sh.t + drow * 136 + nofs);
      *(u32x4*)(vt + ((size_t)(bidx * NH + h) * HD + d) * NSEQ + n0 + nofs) = val;
    }
  }
}

// ---------------- kernel 2: flash attention, 64q blocks @ 4 blocks/CU -----------
// Clean retest of the occupancy axis (R6 was confounded by 19.7M bank conflicts
// + the P roundtrip; both are gone now). Block = 64 q x 4 waves; wave = (qh2,kh2)
// = 32 q x 32 k, in-lane P via the R12 K-row permutation (byte-identical math).
// Grid 1024 = 4 blocks/CU -> 4 waves/SIMD (2x latency hiding, halved chains).
// LDS: 2-buf K/V (32 KB), stage-1-ahead, vmcnt(0) at barrier -- the drain is
// free because STAGE(t+1) was issued a full period (~2000+ cy >> load latency)
// earlier. STAGE targets buf (t+1)%2: read last period, fenced by this barrier;
// faster waves are blocked by barrier t+1 before restaging buf t%2.
__global__ __launch_bounds__(256, 4) void attn_fwd(const _Float16* __restrict__ qg,
                                                   const _Float16* __restrict__ kg,
                                                   const _Float16* __restrict__ vg,
                                                   _Float16* __restrict__ ao) {
  __shared__ _Float16 KVs[4][64 * 64];   // [0..1] K bufs, [2..3] V bufs; 32 KB
  __shared__ float Lred[2][64];

  const int bid = blockIdx.x;
  const int swz = (bid & 7) * 128 + (bid >> 3);    // bijective: 1024 % 8 == 0
  const int bh = swz >> 5, qt = swz & 31;
  const int tid = threadIdx.x, w = tid >> 6, lane = tid & 63;
  const int g = lane >> 4, ln = lane & 15;
  const int sw8 = ln & 7;
  const int qh2 = w >> 1, kh2 = w & 1;

  const _Float16* qp = qg + (size_t)bh * NSEQ * HD;
  const _Float16* kp = kg + (size_t)bh * NSEQ * HD;
  const _Float16* vp = vg + (size_t)bh * HD * NSEQ;

  const int qr0 = qt * 64;

  // Q fragments (B-operand): qf[qb][dk] = Q[qr0+qh2*32+qb*16+ln][dk*32+g*8 ..+8]
  half8 qf[2][2];
#pragma unroll
  for (int qb = 0; qb < 2; ++qb)
#pragma unroll
    for (int dk = 0; dk < 2; ++dk)
      qf[qb][dk] = *(const half8*)(qp + (size_t)(qr0 + qh2 * 32 + qb * 16 + ln) * HD + dk * 32 + g * 8);
  asm volatile("" ::: "memory");   // pin Q loads before staging (vmcnt accounting)

  // staging: wave w loads chunks {2w,2w+1}; K rows permuted per the R12 σ map
  const int rsub = lane >> 3;
  const int csw = ((lane & 7) ^ rsub) << 3;      // within-row bank swizzle (key R&7)
  const int c0 = 2 * w;
  const int R0 = c0 * 8 + rsub, R1 = R0 + 8;
  const int ks0 = 32 * (R0 >> 5) + 8 * ((R0 >> 2) & 3) + 4 * ((R0 >> 4) & 1) + (R0 & 3);
  const int ks1 = 32 * (R1 >> 5) + 8 * ((R1 >> 2) & 3) + 4 * ((R1 >> 4) & 1) + (R1 & 3);

#define STAGE(buf, tt)                                                              \
  {                                                                                 \
    const _Float16* kt_ = kp + (size_t)(tt) * 64 * HD;                              \
    gload_lds16(kt_ + (size_t)ks0 * HD + csw, &KVs[buf][c0 * 512]);                 \
    gload_lds16(kt_ + (size_t)ks1 * HD + csw, &KVs[buf][(c0 + 1) * 512]);           \
    gload_lds16(vp + (size_t)(c0 * 8 + rsub) * NSEQ + (tt) * 64 + csw,              \
                &KVs[2 + (buf)][c0 * 512]);                                         \
    gload_lds16(vp + (size_t)((c0 + 1) * 8 + rsub) * NSEQ + (tt) * 64 + csw,        \
                &KVs[2 + (buf)][(c0 + 1) * 512]);                                   \
  }

  STAGE(0, 0);

  float lsum[2] = {0.f, 0.f};
  f32x4 oacc[4][2];    // [sd][qb]
#pragma unroll
  for (int sd = 0; sd < 4; ++sd)
#pragma unroll
    for (int qb = 0; qb < 2; ++qb) oacc[sd][qb] = (f32x4){0.f, 0.f, 0.f, 0.f};
  const f32x4 fz = (f32x4){0.f, 0.f, 0.f, 0.f};

#define TILE_BODY(kbuf, vbuf)                                                       \
  {                                                                                 \
    const _Float16* kb_ = (kbuf);                                                   \
    const _Float16* vb_ = (vbuf);                                                   \
    f32x4 sacc[2][2];   /* [s][qb] */                                               \
    __builtin_amdgcn_s_setprio(1);                                                  \
    _Pragma("unroll")                                                               \
    for (int s = 0; s < 2; ++s) {                                                   \
      const _Float16* kr = kb_ + (kh2 * 32 + s * 16 + ln) * 64;                     \
      half8 kf0 = *(const half8*)(kr + ((g ^ sw8) << 3));                           \
      half8 kf1 = *(const half8*)(kr + (((4 + g) ^ sw8) << 3));                     \
      _Pragma("unroll")                                                             \
      for (int qb = 0; qb < 2; ++qb) {                                              \
        sacc[s][qb] = __builtin_amdgcn_mfma_f32_16x16x32_f16(kf0, qf[qb][0], fz, 0, 0, 0);          \
        sacc[s][qb] = __builtin_amdgcn_mfma_f32_16x16x32_f16(kf1, qf[qb][1], sacc[s][qb], 0, 0, 0); \
      }                                                                             \
    }                                                                               \
    __builtin_amdgcn_s_setprio(0);                                                  \
    half8 vf[4];   /* V^T[d=sd*16+ln][k = kh2*32 + 8g..+7] */                       \
    _Pragma("unroll")                                                               \
    for (int sd = 0; sd < 4; ++sd)                                                  \
      vf[sd] = *(const half8*)(vb_ + (sd * 16 + ln) * 64 +                          \
                               (((kh2 * 4 + g) ^ sw8) << 3));                       \
    half8 pb[2];                                                                    \
    _Pragma("unroll")                                                               \
    for (int qb = 0; qb < 2; ++qb) {                                                \
      float e0 = __builtin_amdgcn_exp2f(sacc[0][qb][0]);                            \
      float e1 = __builtin_amdgcn_exp2f(sacc[0][qb][1]);                            \
      float e2 = __builtin_amdgcn_exp2f(sacc[0][qb][2]);                            \
      float e3 = __builtin_amdgcn_exp2f(sacc[0][qb][3]);                            \
      float e4 = __builtin_amdgcn_exp2f(sacc[1][qb][0]);                            \
      float e5 = __builtin_amdgcn_exp2f(sacc[1][qb][1]);                            \
      float e6 = __builtin_amdgcn_exp2f(sacc[1][qb][2]);                            \
      float e7 = __builtin_amdgcn_exp2f(sacc[1][qb][3]);                            \
      lsum[qb] += ((e0 + e1) + (e2 + e3)) + ((e4 + e5) + (e6 + e7));                \
      H2U c0_, c1_, c2_, c3_;                                                       \
      c0_.h = __builtin_amdgcn_cvt_pkrtz(e0, e1);                                   \
      c1_.h = __builtin_amdgcn_cvt_pkrtz(e2, e3);                                   \
      c2_.h = __builtin_amdgcn_cvt_pkrtz(e4, e5);                                   \
      c3_.h = __builtin_amdgcn_cvt_pkrtz(e6, e7);                                   \
      union { u32x4 u; half8 h; } pk;                                               \
      pk.u[0] = c0_.u; pk.u[1] = c1_.u; pk.u[2] = c2_.u; pk.u[3] = c3_.u;           \
      pb[qb] = pk.h;                                                                \
    }                                                                               \
    __builtin_amdgcn_s_setprio(1);                                                  \
    _Pragma("unroll")                                                               \
    for (int sd = 0; sd < 4; ++sd)                                                  \
      _Pragma("unroll")                                                             \
      for (int qb = 0; qb < 2; ++qb)                                                \
        oacc[sd][qb] = __builtin_amdgcn_mfma_f32_16x16x32_f16(vf[sd], pb[qb], oacc[sd][qb], 0, 0, 0); \
    __builtin_amdgcn_s_setprio(0);                                                  \
  }

  for (int t = 0; t < 31; ++t) {
    asm volatile("s_waitcnt vmcnt(0)" ::: "memory");   // STAGE(t) landed (issued a full period ago)
    __builtin_amdgcn_s_barrier();                      // all waves done reading buf (t+1)%2
    STAGE((t + 1) & 1, t + 1);
    TILE_BODY(&KVs[t & 1][0], &KVs[2 + (t & 1)][0])
  }
  {  // t = 31: no stage
    asm volatile("s_waitcnt vmcnt(0)" ::: "memory");
    __builtin_amdgcn_s_barrier();
    TILE_BODY(&KVs[1][0], &KVs[3][0])
  }

  // ---- epilogue: cross-g lsum, cross-k-half combine via LDS, store -------------
#pragma unroll
  for (int qb = 0; qb < 2; ++qb) {
    lsum[qb] += __shfl_xor(lsum[qb], 16, 64);
    lsum[qb] += __shfl_xor(lsum[qb], 32, 64);
  }
  __syncthreads();   // all K/V reads done -> buffers reusable as O-partial store
  float* Osh = (float*)&KVs[0][0];   // [64][66] f32 = 16.9 KB over dead 32 KB
  if (g == 0) {
#pragma unroll
    for (int qb = 0; qb < 2; ++qb)
      Lred[kh2][qh2 * 32 + qb * 16 + ln] = lsum[qb];
  }
  if (kh2) {   // k-half-1 waves publish O partials
#pragma unroll
    for (int sd = 0; sd < 4; ++sd)
#pragma unroll
      for (int qb = 0; qb < 2; ++qb)
        *(f32x4*)&Osh[(qh2 * 32 + qb * 16 + ln) * 66 + sd * 16 + g * 4] = oacc[sd][qb];
  }
  __syncthreads();
  if (!kh2) {  // k-half-0 waves combine, normalize, store
    const int bidx = bh >> 4, h = bh & 15;
#pragma unroll
    for (int qb = 0; qb < 2; ++qb) {
      const int q = qh2 * 32 + qb * 16 + ln;
      const float inv = 1.f / (Lred[0][q] + Lred[1][q]);
      const int n = qr0 + q;
#pragma unroll
      for (int sd = 0; sd < 4; ++sd) {
        f32x4 part = *(const f32x4*)&Osh[q * 66 + sd * 16 + g * 4];
        half4 o4;
#pragma unroll
        for (int r = 0; r < 4; ++r) o4[r] = (_Float16)((oacc[sd][qb][r] + part[r]) * inv);
        *(half4*)(ao + (size_t)(bidx * NSEQ + n) * DIMM + h * HD + sd * 16 + g * 4) = o4;
      }
    }
  }
}

// ---------------- kernel 3: out = ao @ w_out^T + b_out, 128x64 tile -------------
__global__ __launch_bounds__(256) void gemm_out(const _Float16* __restrict__ ao,
                                                const _Float16* __restrict__ wout,
                                                const float* __restrict__ bias,
                                                float* __restrict__ out) {
  __shared__ _Float16 As[3 * 128 * 32];   // 24 KB
  __shared__ _Float16 Bs[3 * 64 * 32];    // 12 KB
  f32x4 acc[4][2];
#pragma unroll
  for (int i = 0; i < 4; ++i)
#pragma unroll
    for (int j = 0; j < 2; ++j) acc[i][j] = (f32x4){0.f, 0.f, 0.f, 0.f};
  const int bm = blockIdx.x, bn = blockIdx.y;
  const int am0 = bm * 128, bn0 = bn * 64;

  const int tid = threadIdx.x;
  const int w = tid >> 6, lane = tid & 63;
  const int lr = lane >> 2;
  const int lc = (lane & 3) * 8;
  const int wm = (w >> 1) * 64, wn = (w & 1) * 32;
  const int g = lane >> 4, ln = lane & 15;

#define GSTAGE_O(buf, kk)                                                           \
  {                                                                                 \
    _Pragma("unroll")                                                               \
    for (int i = 0; i < 3; ++i) {                                                   \
      int c = w * 3 + i;                                                            \
      if (c < 8) {                                                                  \
        gload_lds16(ao + (size_t)(am0 + c * 16 + lr) * 1024 + (kk) + lc,            \
                    As + (buf) * 4096 + c * 512);                                   \
      } else {                                                                      \
        int cb = c - 8;                                                             \
        gload_lds16(wout + (size_t)(bn0 + cb * 16 + lr) * 1024 + (kk) + lc,         \
                    Bs + (buf) * 2048 + cb * 512);                                  \
      }                                                                             \
    }                                                                               \
  }

  GSTAGE_O(0, 0)
  GSTAGE_O(1, 32)
  for (int t = 0; t < 32; ++t) {
    if (t < 31) {
      asm volatile("s_waitcnt vmcnt(3)" ::: "memory");
    } else {
      asm volatile("s_waitcnt vmcnt(0)" ::: "memory");
    }
    __builtin_amdgcn_s_barrier();
    if (t < 30) GSTAGE_O((t + 2) % 3, (t + 2) * 32);
    const _Float16* as_ = As + (t % 3) * 4096;
    const _Float16* bs_ = Bs + (t % 3) * 2048;
    half8 af[4], bf[2];
#pragma unroll
    for (int mi = 0; mi < 4; ++mi)
      af[mi] = *(const half8*)(as_ + (wm + mi * 16 + ln) * 32 + g * 8);
#pragma unroll
    for (int ni = 0; ni < 2; ++ni)
      bf[ni] = *(const half8*)(bs_ + (wn + ni * 16 + ln) * 32 + g * 8);
#pragma unroll
    for (int mi = 0; mi < 4; ++mi)
#pragma unroll
      for (int ni = 0; ni < 2; ++ni)
        acc[mi][ni] = __builtin_amdgcn_mfma_f32_16x16x32_f16(af[mi], bf[ni], acc[mi][ni], 0, 0, 0);
  }

#pragma unroll
  for (int mi = 0; mi < 4; ++mi) {
    const int row = bm * 128 + wm + mi * 16 + g * 4;
#pragma unroll
    for (int ni = 0; ni < 2; ++ni) {
      const int col = bn * 64 + wn + ni * 16 + ln;
      const float b = bias[col];
#pragma unroll
      for (int r = 0; r < 4; ++r) out[(size_t)(row + r) * DIMM + col] = acc[mi][ni][r] + b;
    }
  }
}

extern "C" void kernel_launch(void* const* d_in, const int* in_sizes, int n_in,
                              void* d_out, int out_size, void* d_ws, size_t ws_size,
                              hipStream_t stream) {
  const float* x    = (const float*)d_in[0];
  const float* wqkv = (const float*)d_in[1];
  const float* wout = (const float*)d_in[2];
  const float* bout = (const float*)d_in[3];
  float* out = (float*)d_out;

  _Float16* ws = (_Float16*)d_ws;
  _Float16* x_h    = ws;
  _Float16* wqkv_h = ws + (4u << 20);
  _Float16* wout_h = ws + (7u << 20);
  _Float16* q_h    = ws + (8u << 20);   // [b,h,n,64], pre-scaled by 1/32*log2e
  _Float16* k_h    = ws + (12u << 20);  // [b,h,n,64]
  _Float16* vt_h   = ws + (16u << 20);  // [b,h,64,n]
  _Float16* ao_h   = ws + (20u << 20);  // [b*n, 1024]

  cvt_all<<<dim3(4096), 256, 0, stream>>>(x, wqkv, wout, x_h, wqkv_h, wout_h);
  gemm_qkv<<<dim3(32, 24), 256, 0, stream>>>(x_h, wqkv_h, q_h, k_h, vt_h);
  attn_fwd<<<dim3(1024), 256, 0, stream>>>(q_h, k_h, vt_h, ao_h);
  gemm_out<<<dim3(32, 16), 256, 0, stream>>>(ao_h, wout_h, bout, out);
}

// Round 15
// 100.187 us; speedup vs baseline: 1.0917x; 1.0917x over previous
//
#include <hip/hip_runtime.h>

typedef __attribute__((ext_vector_type(8))) _Float16 half8;
typedef __attribute__((ext_vector_type(4))) _Float16 half4;
typedef __attribute__((ext_vector_type(2))) __fp16 fp16x2;
typedef __attribute__((ext_vector_type(4))) float f32x4;
typedef __attribute__((ext_vector_type(4))) unsigned int u32x4;
typedef __attribute__((ext_vector_type(2))) unsigned int u32x2;

#define NSEQ 2048
#define DIMM 1024
#define NH   16
#define HD   64

typedef const void __attribute__((address_space(1))) gvoid_t;
typedef void __attribute__((address_space(3))) svoid_t;

__device__ __forceinline__ void gload_lds16(const void* g, void* l) {
  __builtin_amdgcn_global_load_lds((gvoid_t*)g, (svoid_t*)l, 16, 0, 0);
}

union H2U { fp16x2 h; unsigned int u; };

// ---------------- fused fp32 -> fp16 convert (x, w_qkv, w_out in one launch) ----
__global__ __launch_bounds__(256) void cvt_all(const float* __restrict__ x,
                                               const float* __restrict__ wqkv,
                                               const float* __restrict__ wout,
                                               _Float16* __restrict__ xh,
                                               _Float16* __restrict__ wqkvh,
                                               _Float16* __restrict__ wouth) {
  int i = blockIdx.x * 256 + threadIdx.x;
  const float* src;
  _Float16* dst;
  int off;
  if (i < 524288) { src = x; dst = xh; off = i; }
  else if (i < 917504) { src = wqkv; dst = wqkvh; off = i - 524288; }
  else { src = wout; dst = wouth; off = i - 917504; }
  const float4* p = (const float4*)src + (size_t)off * 2;
  float4 v0 = p[0], v1 = p[1];
  half8 h;
  h[0] = (_Float16)v0.x; h[1] = (_Float16)v0.y; h[2] = (_Float16)v0.z; h[3] = (_Float16)v0.w;
  h[4] = (_Float16)v1.x; h[5] = (_Float16)v1.y; h[6] = (_Float16)v1.z; h[7] = (_Float16)v1.w;
  *((half8*)dst + off) = h;
}

// Q pre-scaled by SCALE * log2(e) so attention works in exp2 domain.
#define QSCALE 0.0450843450f

// ---------------- kernel 1: qkv = x @ w_qkv^T, 256x256 tile, 4-phase ------------
// 8 waves (2M x 4N), BK=32, 3 LDS buffers, counted vmcnt(4) (tile t+2 in flight
// across the wait -- never drains to 0 mid-loop). T2 swizzle both-sides: LDS
// chunk slot ^= (row>>1)&3, realized by pre-swizzled GLOBAL source (G21) +
// swizzled ds_read -> frag reads 2-way (free) instead of 8-way conflicts.
// Per phase: one half-tile of tile t+2 staged (after the phase-top barrier ->
// all waves finished tile t-1 reads of that buffer), 8 MFMAs.
union SmemQ {
  struct { _Float16 A[3 * 8192]; _Float16 B[3 * 8192]; } m;   // 96 KB
  _Float16 t[128 * 264];                                      // 67.5 KB (V-transpose)
};

__global__ __launch_bounds__(512, 1) void gemm_qkv(const _Float16* __restrict__ x,
                                                   const _Float16* __restrict__ wqkv,
                                                   _Float16* __restrict__ qh,
                                                   _Float16* __restrict__ kh,
                                                   _Float16* __restrict__ vt) {
  __shared__ SmemQ sh;
  const int bid = blockIdx.x;
  const int swz = (bid & 7) * 24 + (bid >> 3);   // bijective: 192 % 8 == 0
  const int bm = swz & 15, bn = swz >> 4;
  const int am0 = bm * 256, bn0 = bn * 256;
  const int tid = threadIdx.x, w = tid >> 6, lane = tid & 63;
  const int g = lane >> 4, ln = lane & 15;
  const int wmq = (w >> 2) * 128, wnq = (w & 3) * 64;

  // staging geometry: half-tile = 128 rows x 32 cols (8 KB); 1 load/thread.
  const int srl = tid >> 2;                       // row within half-tile
  const int ssl = (tid & 3) ^ ((srl >> 1) & 3);   // pre-swizzled source chunk
  const int dsto = tid * 8;                       // halfs within half-tile region

#define QSTG(buf, kt, ht)                                                           \
  {                                                                                 \
    if ((ht) < 2) {                                                                 \
      gload_lds16(x + (size_t)(am0 + (ht) * 128 + srl) * 1024 + (kt) * 32 + ssl * 8,\
                  sh.m.A + (buf) * 8192 + (ht) * 4096 + dsto);                      \
    } else {                                                                        \
      gload_lds16(wqkv + (size_t)(bn0 + ((ht) - 2) * 128 + srl) * 1024 +            \
                      (kt) * 32 + ssl * 8,                                          \
                  sh.m.B + (buf) * 8192 + ((ht) - 2) * 4096 + dsto);                \
    }                                                                               \
  }

  f32x4 acc[8][4];
#pragma unroll
  for (int i = 0; i < 8; ++i)
#pragma unroll
    for (int j = 0; j < 4; ++j) acc[i][j] = (f32x4){0.f, 0.f, 0.f, 0.f};

  // prologue: tiles 0 and 1 fully staged (8 loads; oldest 4 = tile 0)
#pragma unroll
  for (int ht = 0; ht < 4; ++ht) QSTG(0, 0, ht)
#pragma unroll
  for (int ht = 0; ht < 4; ++ht) QSTG(1, 1, ht)

  for (int t = 0; t < 32; ++t) {
    const int buf = t % 3;
    const int sbuf = (t + 2) % 3;
    if (t < 31) {
      asm volatile("s_waitcnt vmcnt(4)" ::: "memory");   // tile t resident; t+1 in flight
    } else {
      asm volatile("s_waitcnt vmcnt(0)" ::: "memory");
    }
    __builtin_amdgcn_s_barrier();
    const _Float16* Ab = sh.m.A + buf * 8192;
    const _Float16* Bb = sh.m.B + buf * 8192;
    half8 bf[4];
#pragma unroll
    for (int ni = 0; ni < 4; ++ni) {
      const int r = wnq + ni * 16 + ln;
      bf[ni] = *(const half8*)(Bb + r * 32 + ((g ^ ((r >> 1) & 3)) << 3));
    }
#pragma unroll
    for (int p = 0; p < 4; ++p) {
      const int r0 = wmq + (2 * p) * 16 + ln;
      const int r1 = wmq + (2 * p + 1) * 16 + ln;
      half8 af0 = *(const half8*)(Ab + r0 * 32 + ((g ^ ((r0 >> 1) & 3)) << 3));
      half8 af1 = *(const half8*)(Ab + r1 * 32 + ((g ^ ((r1 >> 1) & 3)) << 3));
      __builtin_amdgcn_s_setprio(1);
#pragma unroll
      for (int ni = 0; ni < 4; ++ni) {
        acc[2 * p][ni]     = __builtin_amdgcn_mfma_f32_16x16x32_f16(af0, bf[ni], acc[2 * p][ni], 0, 0, 0);
        acc[2 * p + 1][ni] = __builtin_amdgcn_mfma_f32_16x16x32_f16(af1, bf[ni], acc[2 * p + 1][ni], 0, 0, 0);
      }
      __builtin_amdgcn_s_setprio(0);
      if (t < 30) QSTG(sbuf, t + 2, p)
      if (p < 3) __builtin_amdgcn_s_barrier();
    }
  }

  // ---- epilogue ----
  const int sec = bn >> 2;            // 0=Q 1=K 2=V
  const int cbase = (bn & 3) * 256;

  if (sec < 2) {
    _Float16* dst = (sec == 0) ? qh : kh;
    const float scale = (sec == 0) ? QSCALE : 1.0f;
#pragma unroll
    for (int mi = 0; mi < 8; ++mi) {
      const int row = am0 + wmq + mi * 16 + g * 4;
      const int bidx = row >> 11, nidx = row & 2047;
#pragma unroll
      for (int ni = 0; ni < 4; ++ni) {
        const int col = cbase + wnq + ni * 16 + ln;
        const int h = col >> 6, d = col & 63;
        _Float16* p = dst + ((size_t)(bidx * NH + h) * NSEQ + nidx) * HD + d;
#pragma unroll
        for (int r = 0; r < 4; ++r) p[r * HD] = (_Float16)(acc[mi][ni][r] * scale);
      }
    }
  } else {
    // V: transpose through dead main-loop LDS, two 128-col passes
    const int bidx = bm >> 3;
    const int n0 = (bm * 256) & 2047;
#pragma unroll
    for (int hc = 0; hc < 2; ++hc) {
      __syncthreads();   // previous reads of sh (loop or prior pass) complete
      if (((w & 3) >> 1) == hc) {
#pragma unroll
        for (int mi = 0; mi < 8; ++mi)
#pragma unroll
          for (int ni = 0; ni < 4; ++ni) {
            const int cl = wnq + ni * 16 + ln - hc * 128;
            const int rowl = wmq + mi * 16 + g * 4;
#pragma unroll
            for (int r = 0; r < 4; ++r)
              sh.t[cl * 264 + rowl + r] = (_Float16)acc[mi][ni][r];
          }
      }
      __syncthreads();
#pragma unroll
      for (int i = 0; i < 8; ++i) {
        const int ci = i * 512 + tid;
        const int cl = ci >> 5, npos = (ci & 31) * 8;
        const int col = cbase + hc * 128 + cl;
        const int h = col >> 6, d = col & 63;
        u32x4 v = *(const u32x4*)(sh.t + cl * 264 + npos);
        *(u32x4*)(vt + ((size_t)(bidx * NH + h) * HD + d) * NSEQ + n0 + npos) = v;
      }
    }
  }
}

// ---------------- kernel 2: flash attention, k-split waves + in-lane P ----------
// (frozen at R13 config: 48.2 us; MfmaUtil ~28, 0 bank conflicts)
__global__ __launch_bounds__(256, 2) void attn_fwd(const _Float16* __restrict__ qg,
                                                   const _Float16* __restrict__ kg,
                                                   const _Float16* __restrict__ vg,
                                                   _Float16* __restrict__ ao) {
  __shared__ _Float16 Ks[3][64 * 64];
  __shared__ _Float16 Vs[3][64 * 64];
  __shared__ float Lred[2][128];

  const int bid = blockIdx.x;
  const int swz = (bid & 7) * 64 + (bid >> 3);     // bijective: 512 % 8 == 0
  const int bh = swz >> 4, qt = swz & 15;
  const int tid = threadIdx.x, w = tid >> 6, lane = tid & 63;
  const int g = lane >> 4, ln = lane & 15;
  const int sw8 = ln & 7;
  const int qh2 = w >> 1, kh2 = w & 1;

  const _Float16* qp = qg + (size_t)bh * NSEQ * HD;
  const _Float16* kp = kg + (size_t)bh * NSEQ * HD;
  const _Float16* vp = vg + (size_t)bh * HD * NSEQ;

  const int qr0 = qt * 128;

  half8 qf[4][2];
#pragma unroll
  for (int qb = 0; qb < 4; ++qb)
#pragma unroll
    for (int dk = 0; dk < 2; ++dk)
      qf[qb][dk] = *(const half8*)(qp + (size_t)(qr0 + qh2 * 64 + qb * 16 + ln) * HD + dk * 32 + g * 8);
  asm volatile("" ::: "memory");

  const int rsub = lane >> 3;
  const int csw = ((lane & 7) ^ rsub) << 3;
  const int c0 = 2 * w;
  const int R0 = c0 * 8 + rsub, R1 = R0 + 8;
  const int ks0 = 32 * (R0 >> 5) + 8 * ((R0 >> 2) & 3) + 4 * ((R0 >> 4) & 1) + (R0 & 3);
  const int ks1 = 32 * (R1 >> 5) + 8 * ((R1 >> 2) & 3) + 4 * ((R1 >> 4) & 1) + (R1 & 3);

#define ASTAGE(buf, tt)                                                             \
  {                                                                                 \
    const _Float16* kt_ = kp + (size_t)(tt) * 64 * HD;                              \
    gload_lds16(kt_ + (size_t)ks0 * HD + csw, &Ks[buf][c0 * 512]);                  \
    gload_lds16(kt_ + (size_t)ks1 * HD + csw, &Ks[buf][(c0 + 1) * 512]);            \
    gload_lds16(vp + (size_t)(c0 * 8 + rsub) * NSEQ + (tt) * 64 + csw,              \
                &Vs[buf][c0 * 512]);                                                \
    gload_lds16(vp + (size_t)((c0 + 1) * 8 + rsub) * NSEQ + (tt) * 64 + csw,        \
                &Vs[buf][(c0 + 1) * 512]);                                          \
  }

  ASTAGE(0, 0);
  ASTAGE(1, 1);

  float lsum[4] = {0.f, 0.f, 0.f, 0.f};
  f32x4 oacc[4][4];
#pragma unroll
  for (int sd = 0; sd < 4; ++sd)
#pragma unroll
    for (int qb = 0; qb < 4; ++qb) oacc[sd][qb] = (f32x4){0.f, 0.f, 0.f, 0.f};
  const f32x4 fz = (f32x4){0.f, 0.f, 0.f, 0.f};

#define TILE_BODY(kbuf, vbuf)                                                       \
  {                                                                                 \
    const _Float16* kb_ = (kbuf);                                                   \
    const _Float16* vb_ = (vbuf);                                                   \
    f32x4 sacc[2][4];                                                               \
    __builtin_amdgcn_s_setprio(1);                                                  \
    _Pragma("unroll")                                                               \
    for (int s = 0; s < 2; ++s) {                                                   \
      const _Float16* kr = kb_ + (kh2 * 32 + s * 16 + ln) * 64;                     \
      half8 kf0 = *(const half8*)(kr + ((g ^ sw8) << 3));                           \
      half8 kf1 = *(const half8*)(kr + (((4 + g) ^ sw8) << 3));                     \
      _Pragma("unroll")                                                             \
      for (int qb = 0; qb < 4; ++qb) {                                              \
        sacc[s][qb] = __builtin_amdgcn_mfma_f32_16x16x32_f16(kf0, qf[qb][0], fz, 0, 0, 0);          \
        sacc[s][qb] = __builtin_amdgcn_mfma_f32_16x16x32_f16(kf1, qf[qb][1], sacc[s][qb], 0, 0, 0); \
      }                                                                             \
    }                                                                               \
    __builtin_amdgcn_s_setprio(0);                                                  \
    half8 vf[4];                                                                    \
    _Pragma("unroll")                                                               \
    for (int sd = 0; sd < 4; ++sd)                                                  \
      vf[sd] = *(const half8*)(vb_ + (sd * 16 + ln) * 64 +                          \
                               (((kh2 * 4 + g) ^ sw8) << 3));                       \
    half8 pb[4];                                                                    \
    _Pragma("unroll")                                                               \
    for (int qb = 0; qb < 4; ++qb) {                                                \
      float e0 = __builtin_amdgcn_exp2f(sacc[0][qb][0]);                            \
      float e1 = __builtin_amdgcn_exp2f(sacc[0][qb][1]);                            \
      float e2 = __builtin_amdgcn_exp2f(sacc[0][qb][2]);                            \
      float e3 = __builtin_amdgcn_exp2f(sacc[0][qb][3]);                            \
      float e4 = __builtin_amdgcn_exp2f(sacc[1][qb][0]);                            \
      float e5 = __builtin_amdgcn_exp2f(sacc[1][qb][1]);                            \
      float e6 = __builtin_amdgcn_exp2f(sacc[1][qb][2]);                            \
      float e7 = __builtin_amdgcn_exp2f(sacc[1][qb][3]);                            \
      lsum[qb] += ((e0 + e1) + (e2 + e3)) + ((e4 + e5) + (e6 + e7));                \
      H2U c0_, c1_, c2_, c3_;                                                       \
      c0_.h = __builtin_amdgcn_cvt_pkrtz(e0, e1);                                   \
      c1_.h = __builtin_amdgcn_cvt_pkrtz(e2, e3);                                   \
      c2_.h = __builtin_amdgcn_cvt_pkrtz(e4, e5);                                   \
      c3_.h = __builtin_amdgcn_cvt_pkrtz(e6, e7);                                   \
      union { u32x4 u; half8 h; } pk;                                               \
      pk.u[0] = c0_.u; pk.u[1] = c1_.u; pk.u[2] = c2_.u; pk.u[3] = c3_.u;           \
      pb[qb] = pk.h;                                                                \
    }                                                                               \
    __builtin_amdgcn_s_setprio(1);                                                  \
    _Pragma("unroll")                                                               \
    for (int sd = 0; sd < 4; ++sd)                                                  \
      _Pragma("unroll")                                                             \
      for (int qb = 0; qb < 4; ++qb)                                                \
        oacc[sd][qb] = __builtin_amdgcn_mfma_f32_16x16x32_f16(vf[sd], pb[qb], oacc[sd][qb], 0, 0, 0); \
    __builtin_amdgcn_s_setprio(0);                                                  \
  }

  for (int t = 0; t < 30; ++t) {
    asm volatile("s_waitcnt vmcnt(4)" ::: "memory");
    __builtin_amdgcn_s_barrier();
    ASTAGE((t + 2) % 3, t + 2);
    TILE_BODY(&Ks[t % 3][0], &Vs[t % 3][0])
  }
  {
    asm volatile("s_waitcnt vmcnt(4)" ::: "memory");
    __builtin_amdgcn_s_barrier();
    TILE_BODY(&Ks[0][0], &Vs[0][0])
  }
  {
    asm volatile("s_waitcnt vmcnt(0)" ::: "memory");
    __builtin_amdgcn_s_barrier();
    TILE_BODY(&Ks[1][0], &Vs[1][0])
  }

#pragma unroll
  for (int qb = 0; qb < 4; ++qb) {
    lsum[qb] += __shfl_xor(lsum[qb], 16, 64);
    lsum[qb] += __shfl_xor(lsum[qb], 32, 64);
  }
  __syncthreads();
  float* Osh = (float*)&Ks[0][0];
  if (g == 0) {
#pragma unroll
    for (int qb = 0; qb < 4; ++qb)
      Lred[kh2][qh2 * 64 + qb * 16 + ln] = lsum[qb];
  }
  if (kh2) {
#pragma unroll
    for (int sd = 0; sd < 4; ++sd)
#pragma unroll
      for (int qb = 0; qb < 4; ++qb)
        *(f32x4*)&Osh[(qh2 * 64 + qb * 16 + ln) * 66 + sd * 16 + g * 4] = oacc[sd][qb];
  }
  __syncthreads();
  if (!kh2) {
    const int bidx = bh >> 4, h = bh & 15;
#pragma unroll
    for (int qb = 0; qb < 4; ++qb) {
      const int q = qh2 * 64 + qb * 16 + ln;
      const float inv = 1.f / (Lred[0][q] + Lred[1][q]);
      const int n = qr0 + q;
#pragma unroll
      for (int sd = 0; sd < 4; ++sd) {
        f32x4 part = *(const f32x4*)&Osh[q * 66 + sd * 16 + g * 4];
        half4 o4;
#pragma unroll
        for (int r = 0; r < 4; ++r) o4[r] = (_Float16)((oacc[sd][qb][r] + part[r]) * inv);
        *(half4*)(ao + (size_t)(bidx * NSEQ + n) * DIMM + h * HD + sd * 16 + g * 4) = o4;
      }
    }
  }
}

// ---------------- kernel 3: out = ao @ w_out^T + b_out, 128x64 tile -------------
__global__ __launch_bounds__(256) void gemm_out(const _Float16* __restrict__ ao,
                                                const _Float16* __restrict__ wout,
                                                const float* __restrict__ bias,
                                                float* __restrict__ out) {
  __shared__ _Float16 As[3 * 128 * 32];   // 24 KB
  __shared__ _Float16 Bs[3 * 64 * 32];    // 12 KB
  f32x4 acc[4][2];
#pragma unroll
  for (int i = 0; i < 4; ++i)
#pragma unroll
    for (int j = 0; j < 2; ++j) acc[i][j] = (f32x4){0.f, 0.f, 0.f, 0.f};
  const int bm = blockIdx.x, bn = blockIdx.y;
  const int am0 = bm * 128, bn0 = bn * 64;

  const int tid = threadIdx.x;
  const int w = tid >> 6, lane = tid & 63;
  const int lr = lane >> 2;
  const int lc = (lane & 3) * 8;
  const int wm = (w >> 1) * 64, wn = (w & 1) * 32;
  const int g = lane >> 4, ln = lane & 15;

#define GSTAGE_O(buf, kk)                                                           \
  {                                                                                 \
    _Pragma("unroll")                                                               \
    for (int i = 0; i < 3; ++i) {                                                   \
      int c = w * 3 + i;                                                            \
      if (c < 8) {                                                                  \
        gload_lds16(ao + (size_t)(am0 + c * 16 + lr) * 1024 + (kk) + lc,            \
                    As + (buf) * 4096 + c * 512);                                   \
      } else {                                                                      \
        int cb = c - 8;                                                             \
        gload_lds16(wout + (size_t)(bn0 + cb * 16 + lr) * 1024 + (kk) + lc,         \
                    Bs + (buf) * 2048 + cb * 512);                                  \
      }                                                                             \
    }                                                                               \
  }

  GSTAGE_O(0, 0)
  GSTAGE_O(1, 32)
  for (int t = 0; t < 32; ++t) {
    if (t < 31) {
      asm volatile("s_waitcnt vmcnt(3)" ::: "memory");
    } else {
      asm volatile("s_waitcnt vmcnt(0)" ::: "memory");
    }
    __builtin_amdgcn_s_barrier();
    if (t < 30) GSTAGE_O((t + 2) % 3, (t + 2) * 32);
    const _Float16* as_ = As + (t % 3) * 4096;
    const _Float16* bs_ = Bs + (t % 3) * 2048;
    half8 af[4], bf[2];
#pragma unroll
    for (int mi = 0; mi < 4; ++mi)
      af[mi] = *(const half8*)(as_ + (wm + mi * 16 + ln) * 32 + g * 8);
#pragma unroll
    for (int ni = 0; ni < 2; ++ni)
      bf[ni] = *(const half8*)(bs_ + (wn + ni * 16 + ln) * 32 + g * 8);
#pragma unroll
    for (int mi = 0; mi < 4; ++mi)
#pragma unroll
      for (int ni = 0; ni < 2; ++ni)
        acc[mi][ni] = __builtin_amdgcn_mfma_f32_16x16x32_f16(af[mi], bf[ni], acc[mi][ni], 0, 0, 0);
  }

#pragma unroll
  for (int mi = 0; mi < 4; ++mi) {
    const int row = bm * 128 + wm + mi * 16 + g * 4;
#pragma unroll
    for (int ni = 0; ni < 2; ++ni) {
      const int col = bn * 64 + wn + ni * 16 + ln;
      const float b = bias[col];
#pragma unroll
      for (int r = 0; r < 4; ++r) out[(size_t)(row + r) * DIMM + col] = acc[mi][ni][r] + b;
    }
  }
}

extern "C" void kernel_launch(void* const* d_in, const int* in_sizes, int n_in,
                              void* d_out, int out_size, void* d_ws, size_t ws_size,
                              hipStream_t stream) {
  const float* x    = (const float*)d_in[0];
  const float* wqkv = (const float*)d_in[1];
  const float* wout = (const float*)d_in[2];
  const float* bout = (const float*)d_in[3];
  float* out = (float*)d_out;

  _Float16* ws = (_Float16*)d_ws;
  _Float16* x_h    = ws;
  _Float16* wqkv_h = ws + (4u << 20);
  _Float16* wout_h = ws + (7u << 20);
  _Float16* q_h    = ws + (8u << 20);   // [b,h,n,64], pre-scaled by 1/32*log2e
  _Float16* k_h    = ws + (12u << 20);  // [b,h,n,64]
  _Float16* vt_h   = ws + (16u << 20);  // [b,h,64,n]
  _Float16* ao_h   = ws + (20u << 20);  // [b*n, 1024]

  cvt_all<<<dim3(4096), 256, 0, stream>>>(x, wqkv, wout, x_h, wqkv_h, wout_h);
  gemm_qkv<<<dim3(192), 512, 0, stream>>>(x_h, wqkv_h, q_h, k_h, vt_h);
  attn_fwd<<<dim3(512), 256, 0, stream>>>(q_h, k_h, vt_h, ao_h);
  gemm_out<<<dim3(32, 16), 256, 0, stream>>>(ao_h, wout_h, bout, out);
}